// Round 10
// baseline (62.089 us; speedup 1.0000x reference)
//
#include <hip/hip_runtime.h>

#define N_NODES   10000
#define M_PAD     10112          // 158 * 64
#define DEG       32
#define IN_FEATS  256
#define HEADS     8
#define OUT_FEATS 64
#define HD        512
#define NEG_SLOPE 0.2f
#define NCHUNK    1250           // chunks of 8 nodes

typedef short bf16x8 __attribute__((ext_vector_type(8)));
typedef float f32x4  __attribute__((ext_vector_type(4)));

__device__ __forceinline__ ushort f2bf(float x) {
    union { float f; unsigned u; } c; c.f = x;
    unsigned r = (c.u + 0x7fffu + ((c.u >> 16) & 1u)) >> 16;   // RNE
    return (ushort)r;
}
__device__ __forceinline__ float bfbits2f(unsigned hi_bits) {  // bits already in [31:16]
    union { unsigned u; float f; } c; c.u = hi_bits;
    return c.f;
}

// ---------------------------------------------------------------------------
// Fused converts: blocks [0,2500) feat fp32->bf16; blocks [2500,2532) W
// transpose+convert to W_bt [N=512][K=256] bf16.   (r4-proven)
// ---------------------------------------------------------------------------
__global__ __launch_bounds__(256) void convert_all(const float* __restrict__ f,
                                                   ushort* __restrict__ fb,
                                                   const float* __restrict__ W,
                                                   ushort* __restrict__ Bt) {
    __shared__ ushort s[64][72];
    const int b = blockIdx.x;
    const int t = threadIdx.x;
    if (b < 2500) {
        const int i = b * 256 + t;   // float4 index
        const float4 v = reinterpret_cast<const float4*>(f)[i];
        ushort4 o;
        o.x = f2bf(v.x); o.y = f2bf(v.y); o.z = f2bf(v.z); o.w = f2bf(v.w);
        reinterpret_cast<ushort4*>(fb)[i] = o;
        return;
    }
    const int bb = b - 2500;             // 0..31
    const int kb = (bb & 3) * 64;
    const int nb = (bb >> 2) * 64;
    #pragma unroll
    for (int rep = 0; rep < 4; ++rep) {
        const int kk = rep * 16 + (t >> 4);
        const int nn = (t & 15) * 4;
        const float4 v = *reinterpret_cast<const float4*>(&W[(size_t)(kb + kk) * HD + nb + nn]);
        s[nn + 0][kk] = f2bf(v.x);
        s[nn + 1][kk] = f2bf(v.y);
        s[nn + 2][kk] = f2bf(v.z);
        s[nn + 3][kk] = f2bf(v.w);
    }
    __syncthreads();
    const int nn = t >> 2;
    const int k0 = (t & 3) * 16;
    #pragma unroll
    for (int c = 0; c < 2; ++c) {
        *reinterpret_cast<uint4*>(&Bt[(size_t)(nb + nn) * IN_FEATS + kb + k0 + c * 8]) =
            *reinterpret_cast<const uint4*>(&s[nn][k0 + c * 8]);
    }
}

// ---------------------------------------------------------------------------
// ft = feat_bf @ W_bt^T. 64x64 tile, BK=32, mfma 16x16x32 bf16.  (r9 form)
// Grid (158, 8) = 1264 blocks; blockIdx.y = head. Fused el/er epilogue with
// cross-wave LDS reduce.
// ---------------------------------------------------------------------------
__global__ __launch_bounds__(256) void gemm_logits(const ushort* __restrict__ A,
                                                   const ushort* __restrict__ Bt,
                                                   const float* __restrict__ attn_l,
                                                   const float* __restrict__ attn_r,
                                                   ushort* __restrict__ C,
                                                   float* __restrict__ el,
                                                   float* __restrict__ er) {
    __shared__ ushort As[64 * 32];
    __shared__ ushort Bs[64 * 32];
    __shared__ float  s_l[2][64];
    __shared__ float  s_r[2][64];

    const int t    = threadIdx.x;
    const int lane = t & 63;
    const int m0   = blockIdx.x * 64;
    const int head = blockIdx.y;
    const int n0   = head * 64;
    const int wave = t >> 6;
    const int wr   = (wave >> 1) * 32;
    const int wc   = (wave & 1) * 32;
    const int wx   = wave & 1;

    const int srow = t >> 2;             // 0..63
    const int sq   = t & 3;
    const int sqs  = sq ^ ((srow >> 1) & 3);

    uint4 ra, rb;
#define LOADREGS(K0)                                                                    \
    do {                                                                                \
        ra = *reinterpret_cast<const uint4*>(A  + (size_t)(m0 + srow) * IN_FEATS + (K0) + sq * 8); \
        rb = *reinterpret_cast<const uint4*>(Bt + (size_t)(n0 + srow) * IN_FEATS + (K0) + sq * 8); \
    } while (0)

    f32x4 acc[2][2];
    #pragma unroll
    for (int i = 0; i < 2; ++i)
        #pragma unroll
        for (int j = 0; j < 2; ++j)
            acc[i][j] = (f32x4){0.f, 0.f, 0.f, 0.f};

    const int rl    = lane & 15;
    const int rqoff = (((lane >> 4) ^ ((rl >> 1) & 3)) * 8);

    LOADREGS(0);
    for (int k0 = 0; k0 < IN_FEATS; k0 += 32) {
        __syncthreads();
        *reinterpret_cast<uint4*>(As + srow * 32 + sqs * 8) = ra;
        *reinterpret_cast<uint4*>(Bs + srow * 32 + sqs * 8) = rb;
        __syncthreads();
        if (k0 + 32 < IN_FEATS) LOADREGS(k0 + 32);

        bf16x8 af[2], bfr[2];
        #pragma unroll
        for (int i = 0; i < 2; ++i)
            af[i] = *reinterpret_cast<const bf16x8*>(As + (wr + i * 16 + rl) * 32 + rqoff);
        #pragma unroll
        for (int j = 0; j < 2; ++j)
            bfr[j] = *reinterpret_cast<const bf16x8*>(Bs + (wc + j * 16 + rl) * 32 + rqoff);
        #pragma unroll
        for (int i = 0; i < 2; ++i)
            #pragma unroll
            for (int j = 0; j < 2; ++j)
                acc[i][j] = __builtin_amdgcn_mfma_f32_16x16x32_bf16(af[i], bfr[j], acc[i][j], 0, 0, 0);
    }
#undef LOADREGS

    const int g = lane >> 4;             // row group 0..3
    float al[2], ar[2];
    #pragma unroll
    for (int j = 0; j < 2; ++j) {
        al[j] = attn_l[n0 + wc + j * 16 + rl];
        ar[j] = attn_r[n0 + wc + j * 16 + rl];
    }

    #pragma unroll
    for (int i = 0; i < 2; ++i) {
        #pragma unroll
        for (int r = 0; r < 4; ++r) {
            const int row = wr + i * 16 + g * 4 + r;   // 0..63 within tile
            const int gm  = m0 + row;
            ushort* dst = C + (size_t)gm * HD + n0 + wc + rl;
            float sl = 0.f, sr = 0.f;
            #pragma unroll
            for (int j = 0; j < 2; ++j) {
                dst[j * 16] = f2bf(acc[i][j][r]);
                sl = fmaf(acc[i][j][r], al[j], sl);
                sr = fmaf(acc[i][j][r], ar[j], sr);
            }
            sl += __shfl_xor(sl, 1, 64); sr += __shfl_xor(sr, 1, 64);
            sl += __shfl_xor(sl, 2, 64); sr += __shfl_xor(sr, 2, 64);
            sl += __shfl_xor(sl, 4, 64); sr += __shfl_xor(sr, 4, 64);
            sl += __shfl_xor(sl, 8, 64); sr += __shfl_xor(sr, 8, 64);
            if (rl == 0) {
                s_l[wx][row] = sl;
                s_r[wx][row] = sr;
            }
        }
    }
    __syncthreads();
    if (t < 64) {
        const int gm = m0 + t;
        if (gm < N_NODES) {
            el[gm * HEADS + head] = s_l[0][t] + s_l[1][t];
            er[gm * HEADS + head] = s_r[0][t] + s_r[1][t];
        }
    }
}

// ---------------------------------------------------------------------------
// Per-node edge softmax -> out_a [E][H][1] (required) + a_t [n][h][j]
// (head-contiguous copy for sliced aggregation).   (r4-proven)
// ---------------------------------------------------------------------------
__global__ __launch_bounds__(256) void softmax_kernel(const float* __restrict__ el,
                                                      const float* __restrict__ er,
                                                      const int* __restrict__ src,
                                                      float* __restrict__ out_a,
                                                      float* __restrict__ a_t) {
    __shared__ int   s_src[DEG];
    __shared__ float s_a[DEG][HEADS];

    const int n = blockIdx.x;
    const int t = threadIdx.x;

    if (t < DEG) s_src[t] = src[n * DEG + t];
    __syncthreads();

    const int h = t >> 5;
    const int j = t & 31;
    const int s = s_src[j];
    float e = el[s * HEADS + h] + er[n * HEADS + h];
    e = (e > 0.f) ? e : NEG_SLOPE * e;

    float m = e;
    #pragma unroll
    for (int msk = 16; msk; msk >>= 1) m = fmaxf(m, __shfl_xor(m, msk, 64));
    const float ex = __expf(e - m);
    float sum = ex;
    #pragma unroll
    for (int msk = 16; msk; msk >>= 1) sum += __shfl_xor(sum, msk, 64);
    s_a[j][h] = ex / sum;
    __syncthreads();

    out_a[(size_t)n * 256 + t] = s_a[t >> 3][t & 7];     // [j][h] layout
    a_t[(size_t)n * 256 + t]   = s_a[t & 31][t >> 5];    // [h][j] layout
}

// ---------------------------------------------------------------------------
// XCD-local aggregation via DISTRIBUTED one-shot claiming.
// 8 replica blocks per chunk; each block reads its XCC_ID and claims a slice
// with one atomicOr on the chunk's line-padded mask (first-free scan starting
// at its own xcc). Pigeonhole => exactly-once coverage of all 8 slices, for
// ANY dispatch->XCD mapping (G16). If dispatch is round-robin, each block gets
// slice == its own XCD -> the gathered 1.28 MB column slice stays L2-resident.
// Exactly 8 atomics per 64B mask line (no hot-line, unlike r5/r8).
// Output is a pure function of (chunk, slice) -> deterministic.
// ---------------------------------------------------------------------------
__global__ __launch_bounds__(256) void agg_claim(const uint* __restrict__ ftb_dw,
                                                 const float* __restrict__ a_t,
                                                 const int* __restrict__ src,
                                                 float* __restrict__ rst,
                                                 int* __restrict__ mask) {
    __shared__ int   s_slice;
    __shared__ int   s_src[8][DEG];
    __shared__ float s_a[8][DEG];

    const int b = blockIdx.x;
    const int c = b >> 3;                // chunk (8 nodes)
    const int t = threadIdx.x;

    if (t == 0) {
        int xcc;
        asm volatile("s_getreg_b32 %0, hwreg(20, 0, 4)" : "=s"(xcc));   // XCC_ID
        int chosen = -1;
        #pragma unroll 1
        for (int k = 0; k < 8; ++k) {
            const int s = (xcc + k) & 7;
            const int old = atomicOr(&mask[c * 16], 1 << s);
            if (!((old >> s) & 1)) { chosen = s; break; }
        }
        s_slice = chosen;
    }
    __syncthreads();
    const int s = s_slice;
    if (s < 0) return;                   // cannot happen (8 replicas, 8 slices); safety

    const int w  = t >> 6;
    const int l  = t & 63;
    const int hi = l >> 5;
    const int li = l & 31;
    const int wn = 2 * w + hi;           // local node 0..7
    const int n  = c * 8 + wn;

    // wave-local staging (each wave writes & reads only rows 2w, 2w+1)
    s_src[wn][li] = src[n * DEG + li];
    s_a[wn][li]   = a_t[(size_t)n * 256 + s * 32 + li];

    const int dwcol = s * 32 + li;       // dword col within the 256-dword row

    uint uv[DEG];
    #pragma unroll
    for (int j = 0; j < DEG; ++j)
        uv[j] = ftb_dw[(size_t)s_src[wn][j] * 256 + dwcol];

    float a0 = 0.f, a1 = 0.f;
    #pragma unroll
    for (int j = 0; j < DEG; ++j) {
        const float wt = s_a[wn][j];
        a0 = fmaf(wt, bfbits2f(uv[j] << 16), a0);
        a1 = fmaf(wt, bfbits2f(uv[j] & 0xffff0000u), a1);
    }
    *reinterpret_cast<float2*>(&rst[(size_t)n * HD + s * 64 + 2 * li]) = make_float2(a0, a1);
}

// ---------------------------------------------------------------------------
extern "C" void kernel_launch(void* const* d_in, const int* in_sizes, int n_in,
                              void* d_out, int out_size, void* d_ws, size_t ws_size,
                              hipStream_t stream) {
    const float* feat   = (const float*)d_in[0];
    const float* W      = (const float*)d_in[1];
    const float* attn_l = (const float*)d_in[2];
    const float* attn_r = (const float*)d_in[3];
    const int*   src    = (const int*)d_in[4];

    float* out_rst = (float*)d_out;                     // [N, H, D]
    float* out_a   = out_rst + (size_t)N_NODES * HD;    // [E, H, 1]

    char* w = (char*)d_ws;
    ushort* feat_bf = (ushort*)w;  w += (size_t)M_PAD * IN_FEATS * 2;   // 5.18 MB
    ushort* W_bt    = (ushort*)w;  w += (size_t)HD * IN_FEATS * 2;      // 0.26 MB
    ushort* ftb     = (ushort*)w;  w += (size_t)M_PAD * HD * 2;         // 10.35 MB
    float*  el      = (float*)w;   w += (size_t)N_NODES * HEADS * 4;
    float*  er      = (float*)w;   w += (size_t)N_NODES * HEADS * 4;
    float*  a_t     = (float*)w;   w += (size_t)N_NODES * 256 * 4;      // 10.24 MB
    int*    mask    = (int*)w;     w += (size_t)NCHUNK * 16 * sizeof(int); // line-padded

    hipMemsetAsync(mask, 0, (size_t)NCHUNK * 16 * sizeof(int), stream);
    convert_all<<<2532, 256, 0, stream>>>(feat, feat_bf, W, W_bt);
    gemm_logits<<<dim3(M_PAD / 64, HEADS), 256, 0, stream>>>(feat_bf, W_bt, attn_l, attn_r,
                                                             ftb, el, er);
    softmax_kernel<<<N_NODES, 256, 0, stream>>>(el, er, src, out_a, a_t);
    agg_claim<<<NCHUNK * 8, 256, 0, stream>>>((const uint*)ftb, a_t, src, out_rst, mask);
}

// Round 11
// 58.705 us; speedup vs baseline: 1.0576x; 1.0576x over previous
//
#include <hip/hip_runtime.h>

#define N_NODES   10000
#define M_PAD     10112          // 158 * 64
#define DEG       32
#define IN_FEATS  256
#define HEADS     8
#define OUT_FEATS 64
#define HD        512
#define NEG_SLOPE 0.2f
#define NCHUNK    1250           // chunks of 8 nodes

typedef short bf16x8 __attribute__((ext_vector_type(8)));
typedef float f32x4  __attribute__((ext_vector_type(4)));

__device__ __forceinline__ ushort f2bf(float x) {
    union { float f; unsigned u; } c; c.f = x;
    unsigned r = (c.u + 0x7fffu + ((c.u >> 16) & 1u)) >> 16;   // RNE
    return (ushort)r;
}
__device__ __forceinline__ float bfbits2f(unsigned hi_bits) {  // bits already in [31:16]
    union { unsigned u; float f; } c; c.u = hi_bits;
    return c.f;
}

// ---------------------------------------------------------------------------
// Fused converts: blocks [0,2500) feat fp32->bf16; blocks [2500,2532) W
// transpose+convert to W_bt [N=512][K=256] bf16.   (r4-proven)
// ---------------------------------------------------------------------------
__global__ __launch_bounds__(256) void convert_all(const float* __restrict__ f,
                                                   ushort* __restrict__ fb,
                                                   const float* __restrict__ W,
                                                   ushort* __restrict__ Bt) {
    __shared__ ushort s[64][72];
    const int b = blockIdx.x;
    const int t = threadIdx.x;
    if (b < 2500) {
        const int i = b * 256 + t;   // float4 index
        const float4 v = reinterpret_cast<const float4*>(f)[i];
        ushort4 o;
        o.x = f2bf(v.x); o.y = f2bf(v.y); o.z = f2bf(v.z); o.w = f2bf(v.w);
        reinterpret_cast<ushort4*>(fb)[i] = o;
        return;
    }
    const int bb = b - 2500;             // 0..31
    const int kb = (bb & 3) * 64;
    const int nb = (bb >> 2) * 64;
    #pragma unroll
    for (int rep = 0; rep < 4; ++rep) {
        const int kk = rep * 16 + (t >> 4);
        const int nn = (t & 15) * 4;
        const float4 v = *reinterpret_cast<const float4*>(&W[(size_t)(kb + kk) * HD + nb + nn]);
        s[nn + 0][kk] = f2bf(v.x);
        s[nn + 1][kk] = f2bf(v.y);
        s[nn + 2][kk] = f2bf(v.z);
        s[nn + 3][kk] = f2bf(v.w);
    }
    __syncthreads();
    const int nn = t >> 2;
    const int k0 = (t & 3) * 16;
    #pragma unroll
    for (int c = 0; c < 2; ++c) {
        *reinterpret_cast<uint4*>(&Bt[(size_t)(nb + nn) * IN_FEATS + kb + k0 + c * 8]) =
            *reinterpret_cast<const uint4*>(&s[nn][k0 + c * 8]);
    }
}

// ---------------------------------------------------------------------------
// ft = feat_bf @ W_bt^T. 64x64 tile, BK=32, mfma 16x16x32 bf16.  (r9-proven)
// Grid (158, 8); blockIdx.y = head. Fused el/er epilogue with cross-wave
// LDS reduce.
// ---------------------------------------------------------------------------
__global__ __launch_bounds__(256) void gemm_logits(const ushort* __restrict__ A,
                                                   const ushort* __restrict__ Bt,
                                                   const float* __restrict__ attn_l,
                                                   const float* __restrict__ attn_r,
                                                   ushort* __restrict__ C,
                                                   float* __restrict__ el,
                                                   float* __restrict__ er) {
    __shared__ ushort As[64 * 32];
    __shared__ ushort Bs[64 * 32];
    __shared__ float  s_l[2][64];
    __shared__ float  s_r[2][64];

    const int t    = threadIdx.x;
    const int lane = t & 63;
    const int m0   = blockIdx.x * 64;
    const int head = blockIdx.y;
    const int n0   = head * 64;
    const int wave = t >> 6;
    const int wr   = (wave >> 1) * 32;
    const int wc   = (wave & 1) * 32;
    const int wx   = wave & 1;

    const int srow = t >> 2;             // 0..63
    const int sq   = t & 3;
    const int sqs  = sq ^ ((srow >> 1) & 3);

    uint4 ra, rb;
#define LOADREGS(K0)                                                                    \
    do {                                                                                \
        ra = *reinterpret_cast<const uint4*>(A  + (size_t)(m0 + srow) * IN_FEATS + (K0) + sq * 8); \
        rb = *reinterpret_cast<const uint4*>(Bt + (size_t)(n0 + srow) * IN_FEATS + (K0) + sq * 8); \
    } while (0)

    f32x4 acc[2][2];
    #pragma unroll
    for (int i = 0; i < 2; ++i)
        #pragma unroll
        for (int j = 0; j < 2; ++j)
            acc[i][j] = (f32x4){0.f, 0.f, 0.f, 0.f};

    const int rl    = lane & 15;
    const int rqoff = (((lane >> 4) ^ ((rl >> 1) & 3)) * 8);

    LOADREGS(0);
    for (int k0 = 0; k0 < IN_FEATS; k0 += 32) {
        __syncthreads();
        *reinterpret_cast<uint4*>(As + srow * 32 + sqs * 8) = ra;
        *reinterpret_cast<uint4*>(Bs + srow * 32 + sqs * 8) = rb;
        __syncthreads();
        if (k0 + 32 < IN_FEATS) LOADREGS(k0 + 32);

        bf16x8 af[2], bfr[2];
        #pragma unroll
        for (int i = 0; i < 2; ++i)
            af[i] = *reinterpret_cast<const bf16x8*>(As + (wr + i * 16 + rl) * 32 + rqoff);
        #pragma unroll
        for (int j = 0; j < 2; ++j)
            bfr[j] = *reinterpret_cast<const bf16x8*>(Bs + (wc + j * 16 + rl) * 32 + rqoff);
        #pragma unroll
        for (int i = 0; i < 2; ++i)
            #pragma unroll
            for (int j = 0; j < 2; ++j)
                acc[i][j] = __builtin_amdgcn_mfma_f32_16x16x32_bf16(af[i], bfr[j], acc[i][j], 0, 0, 0);
    }
#undef LOADREGS

    const int g = lane >> 4;             // row group 0..3
    float al[2], ar[2];
    #pragma unroll
    for (int j = 0; j < 2; ++j) {
        al[j] = attn_l[n0 + wc + j * 16 + rl];
        ar[j] = attn_r[n0 + wc + j * 16 + rl];
    }

    #pragma unroll
    for (int i = 0; i < 2; ++i) {
        #pragma unroll
        for (int r = 0; r < 4; ++r) {
            const int row = wr + i * 16 + g * 4 + r;   // 0..63 within tile
            const int gm  = m0 + row;
            ushort* dst = C + (size_t)gm * HD + n0 + wc + rl;
            float sl = 0.f, sr = 0.f;
            #pragma unroll
            for (int j = 0; j < 2; ++j) {
                dst[j * 16] = f2bf(acc[i][j][r]);
                sl = fmaf(acc[i][j][r], al[j], sl);
                sr = fmaf(acc[i][j][r], ar[j], sr);
            }
            sl += __shfl_xor(sl, 1, 64); sr += __shfl_xor(sr, 1, 64);
            sl += __shfl_xor(sl, 2, 64); sr += __shfl_xor(sr, 2, 64);
            sl += __shfl_xor(sl, 4, 64); sr += __shfl_xor(sr, 4, 64);
            sl += __shfl_xor(sl, 8, 64); sr += __shfl_xor(sr, 8, 64);
            if (rl == 0) {
                s_l[wx][row] = sl;
                s_r[wx][row] = sr;
            }
        }
    }
    __syncthreads();
    if (t < 64) {
        const int gm = m0 + t;
        if (gm < N_NODES) {
            el[gm * HEADS + head] = s_l[0][t] + s_l[1][t];
            er[gm * HEADS + head] = s_r[0][t] + s_r[1][t];
        }
    }
}

// ---------------------------------------------------------------------------
// Per-node edge softmax -> out_a [E][H][1] (required) + a_t [n][h][j]
// (head-contiguous copy for sliced aggregation).   (r4-proven)
// ---------------------------------------------------------------------------
__global__ __launch_bounds__(256) void softmax_kernel(const float* __restrict__ el,
                                                      const float* __restrict__ er,
                                                      const int* __restrict__ src,
                                                      float* __restrict__ out_a,
                                                      float* __restrict__ a_t) {
    __shared__ int   s_src[DEG];
    __shared__ float s_a[DEG][HEADS];

    const int n = blockIdx.x;
    const int t = threadIdx.x;

    if (t < DEG) s_src[t] = src[n * DEG + t];
    __syncthreads();

    const int h = t >> 5;
    const int j = t & 31;
    const int s = s_src[j];
    float e = el[s * HEADS + h] + er[n * HEADS + h];
    e = (e > 0.f) ? e : NEG_SLOPE * e;

    float m = e;
    #pragma unroll
    for (int msk = 16; msk; msk >>= 1) m = fmaxf(m, __shfl_xor(m, msk, 64));
    const float ex = __expf(e - m);
    float sum = ex;
    #pragma unroll
    for (int msk = 16; msk; msk >>= 1) sum += __shfl_xor(sum, msk, 64);
    s_a[j][h] = ex / sum;
    __syncthreads();

    out_a[(size_t)n * 256 + t] = s_a[t >> 3][t & 7];     // [j][h] layout
    a_t[(size_t)n * 256 + t]   = s_a[t & 31][t >> 5];    // [h][j] layout
}

// ---------------------------------------------------------------------------
// Wide-load aggregation: lane owns ONE uint2 (2 adjacent dwords = 4 bf16
// cols, same head), slice covers 2 heads (128 cols). Same bytes as r9's
// 1-dword version, HALF the vector-memory requests, 2x per-lane MLP.
// grid = (1250 chunks) x (4 slice-pairs); static assignment, no atomics.
// Block: 4 waves x 2 nodes; 32 lanes per node.
//   uint2 index s*32+li -> dwords s*64+2li, s*64+2li+1 -> head 2s+(li>>4).
// ---------------------------------------------------------------------------
__global__ __launch_bounds__(256) void agg_wide(const ulong1* __restrict__ ftb_q,
                                                const float* __restrict__ a_t,
                                                const int* __restrict__ src,
                                                float* __restrict__ rst) {
    __shared__ int   s_src[8][DEG];
    __shared__ float s_a[8][2][DEG];

    const int c  = blockIdx.x;           // node chunk (8 nodes)
    const int s  = blockIdx.y;           // slice-pair: heads 2s, 2s+1
    const int t  = threadIdx.x;
    const int w  = t >> 6;
    const int l  = t & 63;
    const int hi = l >> 5;
    const int li = l & 31;
    const int wn = 2 * w + hi;           // local node 0..7
    const int n  = c * 8 + wn;

    // wave-local staging (each wave writes & reads only rows 2w, 2w+1):
    // src (32 ints) + the two heads' a-rows (2 x 32 floats) per node.
    s_src[wn][li] = src[n * DEG + li];
    {
        const float2 av = *reinterpret_cast<const float2*>(
            &a_t[(size_t)n * 256 + (2 * s) * 32 + 2 * li]);
        // a_t[h][j]: element (2s)*32 + 2li is head 2s edge 2li... store straight:
        // simpler: two scalar loads into the [head][edge] table
    }
    s_a[wn][0][li] = a_t[(size_t)n * 256 + (2 * s) * 32 + li];
    s_a[wn][1][li] = a_t[(size_t)n * 256 + (2 * s + 1) * 32 + li];

    const int qcol = s * 32 + li;        // uint2 index within the 128-uint2 row
    const int hsel = li >> 4;            // 0: head 2s (li<16), 1: head 2s+1

    // issue all 32 wide gathers first
    ulong1 uv[DEG];
    #pragma unroll
    for (int j = 0; j < DEG; ++j)
        uv[j] = ftb_q[(size_t)s_src[wn][j] * 128 + qcol];

    float a0 = 0.f, a1 = 0.f, a2 = 0.f, a3 = 0.f;
    #pragma unroll
    for (int j = 0; j < DEG; ++j) {
        const uint lo = (uint)(uv[j].x & 0xffffffffu);
        const uint hi2 = (uint)(uv[j].x >> 32);
        const float wt = s_a[wn][hsel][j];
        a0 = fmaf(wt, bfbits2f(lo << 16), a0);
        a1 = fmaf(wt, bfbits2f(lo & 0xffff0000u), a1);
        a2 = fmaf(wt, bfbits2f(hi2 << 16), a2);
        a3 = fmaf(wt, bfbits2f(hi2 & 0xffff0000u), a3);
    }
    // dwords s*64+2li, s*64+2li+1 -> cols (s*64+2li)*2 .. +3 (4 contiguous)
    float4 o = make_float4(a0, a1, a2, a3);
    *reinterpret_cast<float4*>(&rst[(size_t)n * HD + (size_t)(s * 64 + 2 * li) * 2]) = o;
}

// ---------------------------------------------------------------------------
extern "C" void kernel_launch(void* const* d_in, const int* in_sizes, int n_in,
                              void* d_out, int out_size, void* d_ws, size_t ws_size,
                              hipStream_t stream) {
    const float* feat   = (const float*)d_in[0];
    const float* W      = (const float*)d_in[1];
    const float* attn_l = (const float*)d_in[2];
    const float* attn_r = (const float*)d_in[3];
    const int*   src    = (const int*)d_in[4];

    float* out_rst = (float*)d_out;                     // [N, H, D]
    float* out_a   = out_rst + (size_t)N_NODES * HD;    // [E, H, 1]

    char* w = (char*)d_ws;
    ushort* feat_bf = (ushort*)w;  w += (size_t)M_PAD * IN_FEATS * 2;   // 5.18 MB
    ushort* W_bt    = (ushort*)w;  w += (size_t)HD * IN_FEATS * 2;      // 0.26 MB
    ushort* ftb     = (ushort*)w;  w += (size_t)M_PAD * HD * 2;         // 10.35 MB
    float*  el      = (float*)w;   w += (size_t)N_NODES * HEADS * 4;
    float*  er      = (float*)w;   w += (size_t)N_NODES * HEADS * 4;
    float*  a_t     = (float*)w;   w += (size_t)N_NODES * 256 * 4;      // 10.24 MB

    convert_all<<<2532, 256, 0, stream>>>(feat, feat_bf, W, W_bt);
    gemm_logits<<<dim3(M_PAD / 64, HEADS), 256, 0, stream>>>(feat_bf, W_bt, attn_l, attn_r,
                                                             ftb, el, er);
    softmax_kernel<<<N_NODES, 256, 0, stream>>>(el, er, src, out_a, a_t);
    agg_wide<<<dim3(NCHUNK, 4), 256, 0, stream>>>((const ulong1*)ftb, a_t, src, out_rst);
}

// Round 12
// 55.803 us; speedup vs baseline: 1.1127x; 1.0520x over previous
//
#include <hip/hip_runtime.h>

#define N_NODES   10000
#define M_PAD     10112          // 158 * 64
#define DEG       32
#define IN_FEATS  256
#define HEADS     8
#define OUT_FEATS 64
#define HD        512
#define NEG_SLOPE 0.2f

typedef short bf16x8 __attribute__((ext_vector_type(8)));
typedef float f32x4  __attribute__((ext_vector_type(4)));

__device__ __forceinline__ ushort f2bf(float x) {
    union { float f; unsigned u; } c; c.f = x;
    unsigned r = (c.u + 0x7fffu + ((c.u >> 16) & 1u)) >> 16;   // RNE
    return (ushort)r;
}
__device__ __forceinline__ float bfbits2f(unsigned hi_bits) {  // bits already in [31:16]
    union { unsigned u; float f; } c; c.u = hi_bits;
    return c.f;
}

// ---------------------------------------------------------------------------
// Fused converts: blocks [0,2500) feat fp32->bf16; blocks [2500,2532) W
// transpose+convert to W_bt [N=512][K=256] bf16.   (r4-proven)
// ---------------------------------------------------------------------------
__global__ __launch_bounds__(256) void convert_all(const float* __restrict__ f,
                                                   ushort* __restrict__ fb,
                                                   const float* __restrict__ W,
                                                   ushort* __restrict__ Bt) {
    __shared__ ushort s[64][72];
    const int b = blockIdx.x;
    const int t = threadIdx.x;
    if (b < 2500) {
        const int i = b * 256 + t;   // float4 index
        const float4 v = reinterpret_cast<const float4*>(f)[i];
        ushort4 o;
        o.x = f2bf(v.x); o.y = f2bf(v.y); o.z = f2bf(v.z); o.w = f2bf(v.w);
        reinterpret_cast<ushort4*>(fb)[i] = o;
        return;
    }
    const int bb = b - 2500;             // 0..31
    const int kb = (bb & 3) * 64;
    const int nb = (bb >> 2) * 64;
    #pragma unroll
    for (int rep = 0; rep < 4; ++rep) {
        const int kk = rep * 16 + (t >> 4);
        const int nn = (t & 15) * 4;
        const float4 v = *reinterpret_cast<const float4*>(&W[(size_t)(kb + kk) * HD + nb + nn]);
        s[nn + 0][kk] = f2bf(v.x);
        s[nn + 1][kk] = f2bf(v.y);
        s[nn + 2][kk] = f2bf(v.z);
        s[nn + 3][kk] = f2bf(v.w);
    }
    __syncthreads();
    const int nn = t >> 2;
    const int k0 = (t & 3) * 16;
    #pragma unroll
    for (int c = 0; c < 2; ++c) {
        *reinterpret_cast<uint4*>(&Bt[(size_t)(nb + nn) * IN_FEATS + kb + k0 + c * 8]) =
            *reinterpret_cast<const uint4*>(&s[nn][k0 + c * 8]);
    }
}

// ---------------------------------------------------------------------------
// ft = feat_bf @ W_bt^T. 64x64 tile, BK=32, mfma 16x16x32 bf16.  (r9-proven)
// Grid (158, 8); blockIdx.y = head. Fused el/er epilogue with cross-wave
// LDS reduce.
// ---------------------------------------------------------------------------
__global__ __launch_bounds__(256) void gemm_logits(const ushort* __restrict__ A,
                                                   const ushort* __restrict__ Bt,
                                                   const float* __restrict__ attn_l,
                                                   const float* __restrict__ attn_r,
                                                   ushort* __restrict__ C,
                                                   float* __restrict__ el,
                                                   float* __restrict__ er) {
    __shared__ ushort As[64 * 32];
    __shared__ ushort Bs[64 * 32];
    __shared__ float  s_l[2][64];
    __shared__ float  s_r[2][64];

    const int t    = threadIdx.x;
    const int lane = t & 63;
    const int m0   = blockIdx.x * 64;
    const int head = blockIdx.y;
    const int n0   = head * 64;
    const int wave = t >> 6;
    const int wr   = (wave >> 1) * 32;
    const int wc   = (wave & 1) * 32;
    const int wx   = wave & 1;

    const int srow = t >> 2;             // 0..63
    const int sq   = t & 3;
    const int sqs  = sq ^ ((srow >> 1) & 3);

    uint4 ra, rb;
#define LOADREGS(K0)                                                                    \
    do {                                                                                \
        ra = *reinterpret_cast<const uint4*>(A  + (size_t)(m0 + srow) * IN_FEATS + (K0) + sq * 8); \
        rb = *reinterpret_cast<const uint4*>(Bt + (size_t)(n0 + srow) * IN_FEATS + (K0) + sq * 8); \
    } while (0)

    f32x4 acc[2][2];
    #pragma unroll
    for (int i = 0; i < 2; ++i)
        #pragma unroll
        for (int j = 0; j < 2; ++j)
            acc[i][j] = (f32x4){0.f, 0.f, 0.f, 0.f};

    const int rl    = lane & 15;
    const int rqoff = (((lane >> 4) ^ ((rl >> 1) & 3)) * 8);

    LOADREGS(0);
    for (int k0 = 0; k0 < IN_FEATS; k0 += 32) {
        __syncthreads();
        *reinterpret_cast<uint4*>(As + srow * 32 + sqs * 8) = ra;
        *reinterpret_cast<uint4*>(Bs + srow * 32 + sqs * 8) = rb;
        __syncthreads();
        if (k0 + 32 < IN_FEATS) LOADREGS(k0 + 32);

        bf16x8 af[2], bfr[2];
        #pragma unroll
        for (int i = 0; i < 2; ++i)
            af[i] = *reinterpret_cast<const bf16x8*>(As + (wr + i * 16 + rl) * 32 + rqoff);
        #pragma unroll
        for (int j = 0; j < 2; ++j)
            bfr[j] = *reinterpret_cast<const bf16x8*>(Bs + (wc + j * 16 + rl) * 32 + rqoff);
        #pragma unroll
        for (int i = 0; i < 2; ++i)
            #pragma unroll
            for (int j = 0; j < 2; ++j)
                acc[i][j] = __builtin_amdgcn_mfma_f32_16x16x32_bf16(af[i], bfr[j], acc[i][j], 0, 0, 0);
    }
#undef LOADREGS

    const int g = lane >> 4;             // row group 0..3
    float al[2], ar[2];
    #pragma unroll
    for (int j = 0; j < 2; ++j) {
        al[j] = attn_l[n0 + wc + j * 16 + rl];
        ar[j] = attn_r[n0 + wc + j * 16 + rl];
    }

    #pragma unroll
    for (int i = 0; i < 2; ++i) {
        #pragma unroll
        for (int r = 0; r < 4; ++r) {
            const int row = wr + i * 16 + g * 4 + r;   // 0..63 within tile
            const int gm  = m0 + row;
            ushort* dst = C + (size_t)gm * HD + n0 + wc + rl;
            float sl = 0.f, sr = 0.f;
            #pragma unroll
            for (int j = 0; j < 2; ++j) {
                dst[j * 16] = f2bf(acc[i][j][r]);
                sl = fmaf(acc[i][j][r], al[j], sl);
                sr = fmaf(acc[i][j][r], ar[j], sr);
            }
            sl += __shfl_xor(sl, 1, 64); sr += __shfl_xor(sr, 1, 64);
            sl += __shfl_xor(sl, 2, 64); sr += __shfl_xor(sr, 2, 64);
            sl += __shfl_xor(sl, 4, 64); sr += __shfl_xor(sr, 4, 64);
            sl += __shfl_xor(sl, 8, 64); sr += __shfl_xor(sr, 8, 64);
            if (rl == 0) {
                s_l[wx][row] = sl;
                s_r[wx][row] = sr;
            }
        }
    }
    __syncthreads();
    if (t < 64) {
        const int gm = m0 + t;
        if (gm < N_NODES) {
            el[gm * HEADS + head] = s_l[0][t] + s_l[1][t];
            er[gm * HEADS + head] = s_r[0][t] + s_r[1][t];
        }
    }
}

// ---------------------------------------------------------------------------
// Per-node edge softmax -> out_a [E][H][1] (required) + a_t [n][h][j]
// (head-contiguous copy for sliced aggregation).   (r4-proven)
// ---------------------------------------------------------------------------
__global__ __launch_bounds__(256) void softmax_kernel(const float* __restrict__ el,
                                                      const float* __restrict__ er,
                                                      const int* __restrict__ src,
                                                      float* __restrict__ out_a,
                                                      float* __restrict__ a_t) {
    __shared__ int   s_src[DEG];
    __shared__ float s_a[DEG][HEADS];

    const int n = blockIdx.x;
    const int t = threadIdx.x;

    if (t < DEG) s_src[t] = src[n * DEG + t];
    __syncthreads();

    const int h = t >> 5;
    const int j = t & 31;
    const int s = s_src[j];
    float e = el[s * HEADS + h] + er[n * HEADS + h];
    e = (e > 0.f) ? e : NEG_SLOPE * e;

    float m = e;
    #pragma unroll
    for (int msk = 16; msk; msk >>= 1) m = fmaxf(m, __shfl_xor(m, msk, 64));
    const float ex = __expf(e - m);
    float sum = ex;
    #pragma unroll
    for (int msk = 16; msk; msk >>= 1) sum += __shfl_xor(sum, msk, 64);
    s_a[j][h] = ex / sum;
    __syncthreads();

    out_a[(size_t)n * 256 + t] = s_a[t >> 3][t & 7];     // [j][h] layout
    a_t[(size_t)n * 256 + t]   = s_a[t & 31][t >> 5];    // [h][j] layout
}

// ---------------------------------------------------------------------------
// Sliced aggregation (r4/r9-proven static form): slice = blockIdx&7, chunk =
// blockIdx>>3 (8 nodes). Block: 4 waves x 2 nodes; 32 lanes per node, lane
// owns 1 dword (2 bf16 cols). All 32 gathers issued into registers first.
// ---------------------------------------------------------------------------
__global__ __launch_bounds__(256) void agg_slice(const uint* __restrict__ ftb_dw,
                                                 const float* __restrict__ a_t,
                                                 const int* __restrict__ src,
                                                 float* __restrict__ rst) {
    __shared__ int   s_src[8][DEG];
    __shared__ float s_a[8][DEG];

    const int b  = blockIdx.x;
    const int s  = b & 7;                // head / slice
    const int c  = b >> 3;               // node chunk (8 nodes)
    const int t  = threadIdx.x;
    const int w  = t >> 6;
    const int l  = t & 63;
    const int hi = l >> 5;
    const int li = l & 31;
    const int wn = 2 * w + hi;           // local node 0..7
    const int n  = c * 8 + wn;

    // wave-local staging (each wave writes & reads only rows 2w, 2w+1)
    s_src[wn][li] = src[n * DEG + li];
    s_a[wn][li]   = a_t[(size_t)n * 256 + s * 32 + li];

    const int dwcol = s * 32 + li;       // dword col within the 256-dword row

    uint uv[DEG];
    #pragma unroll
    for (int j = 0; j < DEG; ++j)
        uv[j] = ftb_dw[(size_t)s_src[wn][j] * 256 + dwcol];

    float a0 = 0.f, a1 = 0.f;
    #pragma unroll
    for (int j = 0; j < DEG; ++j) {
        const float wt = s_a[wn][j];
        a0 = fmaf(wt, bfbits2f(uv[j] << 16), a0);
        a1 = fmaf(wt, bfbits2f(uv[j] & 0xffff0000u), a1);
    }
    *reinterpret_cast<float2*>(&rst[(size_t)n * HD + s * 64 + 2 * li]) = make_float2(a0, a1);
}

// ---------------------------------------------------------------------------
extern "C" void kernel_launch(void* const* d_in, const int* in_sizes, int n_in,
                              void* d_out, int out_size, void* d_ws, size_t ws_size,
                              hipStream_t stream) {
    const float* feat   = (const float*)d_in[0];
    const float* W      = (const float*)d_in[1];
    const float* attn_l = (const float*)d_in[2];
    const float* attn_r = (const float*)d_in[3];
    const int*   src    = (const int*)d_in[4];

    float* out_rst = (float*)d_out;                     // [N, H, D]
    float* out_a   = out_rst + (size_t)N_NODES * HD;    // [E, H, 1]

    char* w = (char*)d_ws;
    ushort* feat_bf = (ushort*)w;  w += (size_t)M_PAD * IN_FEATS * 2;   // 5.18 MB
    ushort* W_bt    = (ushort*)w;  w += (size_t)HD * IN_FEATS * 2;      // 0.26 MB
    ushort* ftb     = (ushort*)w;  w += (size_t)M_PAD * HD * 2;         // 10.35 MB
    float*  el      = (float*)w;   w += (size_t)N_NODES * HEADS * 4;
    float*  er      = (float*)w;   w += (size_t)N_NODES * HEADS * 4;
    float*  a_t     = (float*)w;   w += (size_t)N_NODES * 256 * 4;      // 10.24 MB

    convert_all<<<2532, 256, 0, stream>>>(feat, feat_bf, W, W_bt);
    gemm_logits<<<dim3(M_PAD / 64, HEADS), 256, 0, stream>>>(feat_bf, W_bt, attn_l, attn_r,
                                                             ftb, el, er);
    softmax_kernel<<<N_NODES, 256, 0, stream>>>(el, er, src, out_a, a_t);
    agg_slice<<<N_NODES / 8 * 8, 256, 0, stream>>>((const uint*)ftb, a_t, src, out_rst);
}